// Round 4
// baseline (53.929 us; speedup 1.0000x reference)
//
#include <hip/hip_runtime.h>

// FSRS3 scan: inputs (SEQ, BATCH, 2) f32, w (13) f32.
// out = [outputs (SEQ, BATCH, 2) ; final_state (BATCH, 2)] flat f32.
// 1 thread per 2 batch columns, 16B vector streaming, prefetch-by-1 on seq.
// Round 3 -> 4: nontemporal via clang ext_vector float4 (HIP_vector_type
// class is rejected by __builtin_nontemporal_*).

constexpr int SEQ   = 64;
constexpr int BATCH = 262144;

typedef float f4 __attribute__((ext_vector_type(4)));

__device__ __forceinline__ float fexp2(float x) { return __builtin_amdgcn_exp2f(x); }
__device__ __forceinline__ float flog2(float x) { return __builtin_amdgcn_logf(x); }
__device__ __forceinline__ float frcp(float x)  { return __builtin_amdgcn_rcpf(x); }

__global__ __launch_bounds__(256)
void fsrs3_kernel(const float* __restrict__ in,
                  const float* __restrict__ w_,
                  float* __restrict__ out) {
    const int tid = blockIdx.x * blockDim.x + threadIdx.x;   // 0 .. BATCH/2-1

    const float w0 = w_[0],  w1 = w_[1],  w2 = w_[2],  w3 = w_[3];
    const float w4 = w_[4],  w5 = w_[5],  w6 = w_[6],  w7 = w_[7];
    const float w8 = w_[8],  w9 = w_[9],  w10 = w_[10], w11 = w_[11];
    const float w12 = w_[12];

    constexpr float L2E      = 1.44269504088896340736f;   // log2(e)
    constexpr float LOG2_09  = -0.15200309344504997f;     // log2(0.9)
    const float ew6  = fexp2(w6 * L2E);                   // exp(w6)
    const float w8l  = w8  * L2E;
    const float w12l = w12 * L2E;
    const float omw5 = 1.0f - w5;
    const float w52  = w5 * w2;

    const f4* __restrict__ inp  = (const f4*)in;
    f4*       __restrict__ outp = (f4*)out;
    constexpr int RS = BATCH / 2;   // f4 per seq row

    // ---- first step (seq 0): state from rating only ----
    f4 x = __builtin_nontemporal_load(&inp[tid]);
    float s0, d0, s1, d1;
    {
        const float r0 = x.y, r1 = x.w;
        s0 = fminf(fmaxf(w0 + w1 * (r0 - 1.0f), 0.1f), 36500.0f);
        d0 = fminf(fmaxf(w2 + w3 * (r0 - 3.0f), 1.0f), 10.0f);
        s1 = fminf(fmaxf(w0 + w1 * (r1 - 1.0f), 0.1f), 36500.0f);
        d1 = fminf(fmaxf(w2 + w3 * (r1 - 3.0f), 1.0f), 10.0f);
    }
    {
        f4 o = {s0, d0, s1, d1};
        __builtin_nontemporal_store(o, &outp[tid]);
    }

    // ---- recurrence, seq 1..63, prefetch next row by one iteration ----
    x = __builtin_nontemporal_load(&inp[RS + tid]);

    auto step = [&](float t, float rating, float& s, float& d) {
        const float r   = fexp2(LOG2_09 * t * frcp(s));   // 0.9^(t/s)
        const float nd  = fminf(fmaxf(w52 + omw5 * (d + w4 * (rating - 3.0f)),
                                      1.0f), 10.0f);
        const float omr = 1.0f - r;
        const float ls  = flog2(s);
        const float e8  = fexp2(omr * w8l);           // exp((1-r)*w8)
        const float e12 = fexp2(omr * w12l);          // exp((1-r)*w12)
        const float p7  = fexp2(w7  * ls);            // s^w7
        const float p11 = fexp2(w11 * ls);            // s^w11
        const float pnd = fexp2(w10 * flog2(nd));     // nd^w10
        const float succ = s * (1.0f + ew6 * (11.0f - nd) * p7 * (e8 - 1.0f));
        const float fail = w9 * pnd * p11 * e12;
        const float ns   = (rating > 1.0f) ? succ : fail;
        s = fminf(fmaxf(ns, 0.1f), 36500.0f);
        d = nd;
    };

    for (int seq = 1; seq < SEQ; ++seq) {
        const int pn = (seq + 1 < SEQ) ? (seq + 1) : (SEQ - 1);
        f4 xn = __builtin_nontemporal_load(&inp[(long long)pn * RS + tid]);

        step(x.x, x.y, s0, d0);
        step(x.z, x.w, s1, d1);

        f4 o = {s0, d0, s1, d1};
        __builtin_nontemporal_store(o, &outp[(long long)seq * RS + tid]);
        x = xn;
    }

    // ---- final_state duplicate at the tail ----
    {
        f4 o = {s0, d0, s1, d1};
        __builtin_nontemporal_store(o, &outp[(long long)SEQ * RS + tid]);
    }
}

extern "C" void kernel_launch(void* const* d_in, const int* in_sizes, int n_in,
                              void* d_out, int out_size, void* d_ws, size_t ws_size,
                              hipStream_t stream) {
    const float* in = (const float*)d_in[0];
    const float* w  = (const float*)d_in[1];
    float* out      = (float*)d_out;

    dim3 block(256);
    dim3 grid((BATCH / 2) / 256);   // 512 blocks
    hipLaunchKernelGGL(fsrs3_kernel, grid, block, 0, stream, in, w, out);
}

// Round 5
// 48.270 us; speedup vs baseline: 1.1172x; 1.1172x over previous
//
#include <hip/hip_runtime.h>

// FSRS3 scan: inputs (SEQ, BATCH, 2) f32, w (13) f32.
// out = [outputs (SEQ, BATCH, 2) ; final_state (BATCH, 2)] flat f32.
// 1 thread per 2 batch columns, 16B vector streaming.
// Round 4 -> 5: revert nontemporal (hurt -15%: L2 write-combining of the
// store stream is a win, not churn). Deepen seq-axis prefetch to 2 rows
// outstanding: 2048 waves x 1KB was ~2MB in flight vs ~2.4MB needed at
// 900cy HBM latency; 2-deep doubles it.

constexpr int SEQ   = 64;
constexpr int BATCH = 262144;

typedef float f4 __attribute__((ext_vector_type(4)));

__device__ __forceinline__ float fexp2(float x) { return __builtin_amdgcn_exp2f(x); }
__device__ __forceinline__ float flog2(float x) { return __builtin_amdgcn_logf(x); }
__device__ __forceinline__ float frcp(float x)  { return __builtin_amdgcn_rcpf(x); }

__global__ __launch_bounds__(256)
void fsrs3_kernel(const float* __restrict__ in,
                  const float* __restrict__ w_,
                  float* __restrict__ out) {
    const int tid = blockIdx.x * blockDim.x + threadIdx.x;   // 0 .. BATCH/2-1

    const float w0 = w_[0],  w1 = w_[1],  w2 = w_[2],  w3 = w_[3];
    const float w4 = w_[4],  w5 = w_[5],  w6 = w_[6],  w7 = w_[7];
    const float w8 = w_[8],  w9 = w_[9],  w10 = w_[10], w11 = w_[11];
    const float w12 = w_[12];

    constexpr float L2E      = 1.44269504088896340736f;   // log2(e)
    constexpr float LOG2_09  = -0.15200309344504997f;     // log2(0.9)
    const float ew6  = fexp2(w6 * L2E);                   // exp(w6)
    const float w8l  = w8  * L2E;
    const float w12l = w12 * L2E;
    const float omw5 = 1.0f - w5;
    const float w52  = w5 * w2;

    const f4* __restrict__ inp  = (const f4*)in;
    f4*       __restrict__ outp = (f4*)out;
    constexpr int RS = BATCH / 2;   // f4 per seq row

    // ---- first step (seq 0): state from rating only ----
    f4 x = inp[tid];
    float s0, d0, s1, d1;
    {
        const float r0 = x.y, r1 = x.w;
        s0 = fminf(fmaxf(w0 + w1 * (r0 - 1.0f), 0.1f), 36500.0f);
        d0 = fminf(fmaxf(w2 + w3 * (r0 - 3.0f), 1.0f), 10.0f);
        s1 = fminf(fmaxf(w0 + w1 * (r1 - 1.0f), 0.1f), 36500.0f);
        d1 = fminf(fmaxf(w2 + w3 * (r1 - 3.0f), 1.0f), 10.0f);
    }
    {
        f4 o = {s0, d0, s1, d1};
        outp[tid] = o;
    }

    // ---- recurrence, seq 1..63, 2-deep prefetch on the seq axis ----
    f4 xc = inp[(long long)1 * RS + tid];     // row seq=1 (current)
    f4 xn = inp[(long long)2 * RS + tid];     // row seq=2 (next)

    auto step = [&](float t, float rating, float& s, float& d) {
        const float r   = fexp2(LOG2_09 * t * frcp(s));   // 0.9^(t/s)
        const float nd  = fminf(fmaxf(w52 + omw5 * (d + w4 * (rating - 3.0f)),
                                      1.0f), 10.0f);
        const float omr = 1.0f - r;
        const float ls  = flog2(s);
        const float e8  = fexp2(omr * w8l);           // exp((1-r)*w8)
        const float e12 = fexp2(omr * w12l);          // exp((1-r)*w12)
        const float p7  = fexp2(w7  * ls);            // s^w7
        const float p11 = fexp2(w11 * ls);            // s^w11
        const float pnd = fexp2(w10 * flog2(nd));     // nd^w10
        const float succ = s * (1.0f + ew6 * (11.0f - nd) * p7 * (e8 - 1.0f));
        const float fail = w9 * pnd * p11 * e12;
        const float ns   = (rating > 1.0f) ? succ : fail;
        s = fminf(fmaxf(ns, 0.1f), 36500.0f);
        d = nd;
    };

    for (int seq = 1; seq < SEQ; ++seq) {
        const int p2 = (seq + 2 < SEQ) ? (seq + 2) : (SEQ - 1);
        f4 x2 = inp[(long long)p2 * RS + tid];    // issue row seq+2

        step(xc.x, xc.y, s0, d0);
        step(xc.z, xc.w, s1, d1);

        f4 o = {s0, d0, s1, d1};
        outp[(long long)seq * RS + tid] = o;

        xc = xn;
        xn = x2;
    }

    // ---- final_state duplicate at the tail ----
    {
        f4 o = {s0, d0, s1, d1};
        outp[(long long)SEQ * RS + tid] = o;
    }
}

extern "C" void kernel_launch(void* const* d_in, const int* in_sizes, int n_in,
                              void* d_out, int out_size, void* d_ws, size_t ws_size,
                              hipStream_t stream) {
    const float* in = (const float*)d_in[0];
    const float* w  = (const float*)d_in[1];
    float* out      = (float*)d_out;

    dim3 block(256);
    dim3 grid((BATCH / 2) / 256);   // 512 blocks
    hipLaunchKernelGGL(fsrs3_kernel, grid, block, 0, stream, in, w, out);
}